// Round 15
// baseline (208.638 us; speedup 1.0000x reference)
//
#include <hip/hip_runtime.h>
#include <math.h>

#define DEV __device__ __forceinline__

constexpr int IN   = 1024;   // input features (K)
constexpr int OUT  = 1024;   // output features (N)
constexpr int NC   = 8;      // GMM components
constexpr int MAXM = 96;     // max missing entries tracked per row (Poisson(20.5): P(>96) ~ 1e-40)

typedef __bf16 bf16x8 __attribute__((ext_vector_type(8)));
typedef float  f32x4  __attribute__((ext_vector_type(4)));
typedef float  f32x2  __attribute__((ext_vector_type(2)));
typedef unsigned short u16x8 __attribute__((ext_vector_type(8)));
typedef unsigned int u32;

union ABf { bf16x8 v; u32 d[4]; unsigned short s[8]; };

DEV unsigned short f2bf(float f) {   // RNE float->bf16, input guaranteed non-NaN
  union { float f; u32 u; } v; v.f = f;
  u32 u = v.u;
  return (unsigned short)((u + 0x7FFFu + ((u >> 16) & 1u)) >> 16);
}

DEV float bfbits2f(u32 bits) {       // f32 whose high16 = bf16 bits
  union { u32 u; float f; } v; v.u = bits;
  return v.f;
}

DEV u32 pkclean(float a, float b) {  // NaN->0, RNE pack to (bf16(a) | bf16(b)<<16)
  a = (a != a) ? 0.f : a;
  b = (b != b) ? 0.f : b;
  u32 r;
  asm("v_cvt_pk_bf16_f32 %0, %1, %2" : "=v"(r) : "v"(a), "v"(b));
  return r;
}

DEV void gload_lds16(const void* g, void* l) {
  __builtin_amdgcn_global_load_lds(
      (__attribute__((address_space(1))) void*)(unsigned long long)(uintptr_t)g,
      (__attribute__((address_space(3))) void*)l,
      16, 0, 0);
}

// ---------------------------------------------------------------------------
// K1: per-row NaN scan -> deterministic (sorted) missing index list + count.
// (No xb output anymore: the GEMM reads x directly.)  Pad slots zero-filled.
// ---------------------------------------------------------------------------
__global__ __launch_bounds__(256) void prep_kernel(
    const float* __restrict__ x,
    unsigned short* __restrict__ midx, int* __restrict__ counts) {
  const int row = blockIdx.x, t = threadIdx.x;
  __shared__ int ps[256];

  float4 v = ((const float4*)x)[row * (IN / 4) + t];  // cols 4t..4t+3
  bool n0 = (v.x != v.x), n1 = (v.y != v.y), n2 = (v.z != v.z), n3 = (v.w != v.w);

  int lc = (int)n0 + (int)n1 + (int)n2 + (int)n3;
  ps[t] = lc;
  __syncthreads();
  for (int off = 1; off < 256; off <<= 1) {
    int add = (t >= off) ? ps[t - off] : 0;
    __syncthreads();
    ps[t] += add;
    __syncthreads();
  }
  int pos = ps[t] - lc;  // exclusive prefix
  int col = 4 * t;
  if (n0) { if (pos < MAXM) midx[row * MAXM + pos] = (unsigned short)(col + 0); pos++; }
  if (n1) { if (pos < MAXM) midx[row * MAXM + pos] = (unsigned short)(col + 1); pos++; }
  if (n2) { if (pos < MAXM) midx[row * MAXM + pos] = (unsigned short)(col + 2); pos++; }
  if (n3) { if (pos < MAXM) midx[row * MAXM + pos] = (unsigned short)(col + 3); pos++; }
  if (t == 255) counts[row] = min(ps[255], MAXM);
  __syncthreads();
  int mm = min(ps[255], MAXM);
  for (int idx = mm + t; idx < MAXM; idx += 256) midx[row * MAXM + idx] = 0;
}

// ---------------------------------------------------------------------------
// K1b: W [IN][OUT] f32 -> Wt [OUT][IN] bf16 (GEMM B^T) AND W16 [IN][OUT] bf16
// (row-major, epilogue A-gathers). Block (0,0) computes softmax(gw)->p_ws.
// ---------------------------------------------------------------------------
__global__ __launch_bounds__(256) void transpose_w(
    const float* __restrict__ W, unsigned short* __restrict__ Wt,
    unsigned short* __restrict__ W16,
    const float* __restrict__ gw, float* __restrict__ p_ws) {
  __shared__ float tile[32][33];
  const int k0 = blockIdx.x * 32, n0 = blockIdx.y * 32;
  const int tx = threadIdx.x, ty = threadIdx.y;

  if (k0 == 0 && n0 == 0 && tx == 0 && ty == 0) {
    float wmax = -1e30f;
    for (int i = 0; i < NC; ++i) wmax = fmaxf(wmax, gw[i]);
    float e[NC], s = 0.f;
    for (int i = 0; i < NC; ++i) { e[i] = expf(gw[i] - wmax); s += e[i]; }
    for (int i = 0; i < NC; ++i) p_ws[i] = e[i] / s;
  }

  for (int r = ty; r < 32; r += 8) {
    float v = W[(k0 + r) * OUT + (n0 + tx)];
    tile[r][tx] = v;
    W16[(k0 + r) * OUT + (n0 + tx)] = f2bf(v);
  }
  __syncthreads();
  for (int r = ty; r < 32; r += 8) Wt[(n0 + r) * IN + (k0 + tx)] = f2bf(tile[tx][r]);
}

// ---------------------------------------------------------------------------
// K2: base = clean(x) @ Wt^T. 128x128 tile, BK=32, 4 waves (m97 structure).
// A-path now reg-staged from f32 x (NaN-clean + cvt_pk inline); B-path keeps
// gload_lds16 from Wt. Fragment layout / MFMA / C-write identical to R1-R13.
// ---------------------------------------------------------------------------
__global__ __launch_bounds__(256) void gemm_base(
    const float* __restrict__ x, const unsigned short* __restrict__ Bt,
    float* __restrict__ C, int M) {
  __shared__ __align__(16) unsigned short sA[128 * 32];
  __shared__ __align__(16) unsigned short sB[128 * 32];

  const int t = threadIdx.x;
  const int lane = t & 63, w = t >> 6;
  const int wm = w >> 1, wn = w & 1;
  const int l15 = lane & 15, kblk = lane >> 4;
  const int row0 = blockIdx.x * 128, col0 = blockIdx.y * 128;

  const int arow = t >> 1;          // A staging: row 0..127
  const int kh   = (t & 1) * 16;    // k-half {0,16}
  const int r_b  = t >> 2;          // B staging row 0..63
  const int cb_b = (t & 3) * 8;

  f32x4 acc[4][4] = {};

  const int aoff = (wm * 64 + l15) * 32 + kblk * 8;
  const int boff = (wn * 64 + l15) * 32 + kblk * 8;

  for (int k0 = 0; k0 < IN; k0 += 32) {
    __syncthreads();
    // B: async to LDS
    gload_lds16(&Bt[(size_t)(col0 + r_b) * IN + k0 + cb_b],      &sB[t * 8]);
    gload_lds16(&Bt[(size_t)(col0 + r_b + 64) * IN + k0 + cb_b], &sB[2048 + t * 8]);
    // A: reg-stage from x (NaN-clean + bf16 pack)
    {
      const float* xs = x + (size_t)(row0 + arow) * IN + k0 + kh;
      float4 v0 = *(const float4*)(xs + 0);
      float4 v1 = *(const float4*)(xs + 4);
      float4 v2 = *(const float4*)(xs + 8);
      float4 v3 = *(const float4*)(xs + 12);
      u32 pk[8];
      pk[0] = pkclean(v0.x, v0.y); pk[1] = pkclean(v0.z, v0.w);
      pk[2] = pkclean(v1.x, v1.y); pk[3] = pkclean(v1.z, v1.w);
      pk[4] = pkclean(v2.x, v2.y); pk[5] = pkclean(v2.z, v2.w);
      pk[6] = pkclean(v3.x, v3.y); pk[7] = pkclean(v3.z, v3.w);
      *(uint4*)&sA[arow * 32 + kh + 0] = *(uint4*)&pk[0];
      *(uint4*)&sA[arow * 32 + kh + 8] = *(uint4*)&pk[4];
    }
    __syncthreads();  // ds_write + gload_lds drained before frag reads

    bf16x8 af[4], bfr[4];
#pragma unroll
    for (int mi = 0; mi < 4; ++mi) af[mi]  = *(const bf16x8*)&sA[aoff + mi * 16 * 32];
#pragma unroll
    for (int ni = 0; ni < 4; ++ni) bfr[ni] = *(const bf16x8*)&sB[boff + ni * 16 * 32];
#pragma unroll
    for (int mi = 0; mi < 4; ++mi)
#pragma unroll
      for (int ni = 0; ni < 4; ++ni)
        acc[mi][ni] = __builtin_amdgcn_mfma_f32_16x16x32_bf16(af[mi], bfr[ni], acc[mi][ni], 0, 0, 0);
  }

#pragma unroll
  for (int mi = 0; mi < 4; ++mi)
#pragma unroll
    for (int ni = 0; ni < 4; ++ni) {
      int grow = row0 + wm * 64 + mi * 16 + kblk * 4;
      int gcol = col0 + wn * 64 + ni * 16 + l15;
#pragma unroll
      for (int r = 0; r < 4; ++r)
        C[(size_t)(grow + r) * OUT + gcol] = acc[mi][ni][r];
    }
}

// ---------------------------------------------------------------------------
// K3 (MFMA v7 = R13's verified structure, u16 gathers + bigger VGPR budget):
//   - A elems loaded as u16 from W16 bf16 copy (pack = or/shl, no cvt);
//     __launch_bounds__(256,2) -> 256-VGPR budget so the pipeline state can
//     be register-resident (R13/R14's 64-VGPR cap re-serialized the loads)
//   - 2-deep tile pipeline, no LDS, no barriers (R13-proven)
// nr()/shfl readout verbatim (R9/R13-verified, absmax 0.5).
// ---------------------------------------------------------------------------
__global__ __launch_bounds__(256, 2) void epilogue_mfma7(
    float* __restrict__ io, const unsigned short* __restrict__ W16,
    const float* __restrict__ bvec, const float* __restrict__ p_ws,
    const float* __restrict__ gmean, const float* __restrict__ gcov,
    const unsigned short* __restrict__ midx, const int* __restrict__ counts) {
  const int row = blockIdx.x;
  const int cb  = blockIdx.y * 512;
  const int t   = threadIdx.x;
  const int lane = t & 63, wvi = t >> 6;
  const int nn = lane & 15, ii = lane & 7, g = lane >> 4;
  const bool isCov = nn >= 8;

  const int m = counts[row];

  if (m == 0) {  // full row: relu (uniform; essentially never taken at 2% miss)
    int c = cb + 2 * t;
    f32x2 bb = *(const f32x2*)(io + (size_t)row * OUT + c);
    f32x2 bi = *(const f32x2*)(bvec + c);
    f32x2 r; r[0] = fmaxf(bb[0] + bi[0], 0.f); r[1] = fmaxf(bb[1] + bi[1], 0.f);
    *(f32x2*)(io + (size_t)row * OUT + c) = r;
    return;
  }

  const int nch = (m + 31) >> 5;
  const unsigned short* mrow = midx + (size_t)row * MAXM;

  const unsigned colA = (unsigned)(cb + wvi * 128 + nn);  // lane's col (+16/tile)
  const float* gsrc = (isCov ? gcov : gmean) + ii * IN;   // comp source row

  f32x4 acc[8] = {};

  for (int ch = 0; ch < nch; ++ch) {
    // lane's 8 k-slots: one 16B load (pad region zero-filled by prep)
    u16x8 kvv = *(const u16x8*)&mrow[ch * 32 + g * 8];

    unsigned aoff[8];
#pragma unroll
    for (int j = 0; j < 8; ++j) aoff[j] = ((unsigned)kvv[j] << 10) + colA;

    // ---- B fragment: (mean | |cov|) for comp ii, slots g*8..g*8+7 ----
    float bv[8];
#pragma unroll
    for (int j = 0; j < 8; ++j) {
      float v = gsrc[kvv[j]];
      if (isCov) v = fabsf(v);
      bv[j] = (ch * 32 + g * 8 + j < m) ? v : 0.f;       // zero padded slots
    }
    ABf vals;
#pragma unroll
    for (int j = 0; j < 4; ++j)
      asm("v_cvt_pk_bf16_f32 %0, %1, %2" : "=v"(vals.d[j]) : "v"(bv[2*j]), "v"(bv[2*j+1]));
    ABf zf; zf.d[0] = zf.d[1] = zf.d[2] = zf.d[3] = 0;
    bf16x8 bm = isCov ? zf.v : vals.v;   // mean half (N-cols 0..7)
    bf16x8 bc = isCov ? vals.v : zf.v;   // cov  half (N-cols 8..15)

    // ---- A pipeline: 8 col-tiles, 2-deep, u16 gathers ----
    unsigned short cur[8], nxt[8];
#pragma unroll
    for (int j = 0; j < 8; ++j) cur[j] = W16[aoff[j]];           // tile 0
#pragma unroll
    for (int tl = 0; tl < 8; ++tl) {
      if (tl < 7) {
#pragma unroll
        for (int j = 0; j < 8; ++j) nxt[j] = W16[aoff[j] + (tl + 1) * 16];
      }
      ABf aw, a2;
#pragma unroll
      for (int p = 0; p < 4; ++p)
        aw.d[p] = (u32)cur[2*p] | ((u32)cur[2*p+1] << 16);       // bf16 bits as-is
#pragma unroll
      for (int p = 0; p < 4; ++p) {
        float lo = bfbits2f(aw.d[p] << 16);
        float hi = bfbits2f(aw.d[p] & 0xFFFF0000u);
        float q0 = lo * lo, q1 = hi * hi;
        asm("v_cvt_pk_bf16_f32 %0, %1, %2" : "=v"(a2.d[p]) : "v"(q0), "v"(q1));
      }
      acc[tl] = __builtin_amdgcn_mfma_f32_16x16x32_bf16(aw.v, bm, acc[tl], 0, 0, 0);
      acc[tl] = __builtin_amdgcn_mfma_f32_16x16x32_bf16(a2.v, bc, acc[tl], 0, 0, 0);
#pragma unroll
      for (int j = 0; j < 8; ++j) cur[j] = nxt[j];
    }
  }

  // ---- nr() epilogue (R9/R13-verified readout) ----
  const float INV_SQRT_2PI = 0.39894228040143268f;
  const float LOGI_K = 1.702f;
  const float L2E = 1.442695040888963f;
  const float pi_w = p_ws[ii];
  const int rrb = isCov ? 2 : 0;

#pragma unroll
  for (int tl = 0; tl < 8; ++tl) {
    f32x4 ac = acc[tl];
    float s0 = __shfl_xor(ac[0], 8);
    float s1 = __shfl_xor(ac[1], 8);
    float s2 = __shfl_xor(ac[2], 8);
    float s3 = __shfl_xor(ac[3], 8);
    float A0 = isCov ? s2 : ac[0];
    float A1 = isCov ? s3 : ac[1];
    float V0 = isCov ? ac[2] : s0;
    float V1 = isCov ? ac[3] : s1;

    int c = cb + wvi * 128 + tl * 16 + g * 4 + rrb;
    f32x2 bb = *(const f32x2*)(io + (size_t)row * OUT + c);
    f32x2 bi = *(const f32x2*)(bvec + c);

    float t0, t1;
    {
      float a   = bb[0] + bi[0] + A0;
      float rs  = (V0 > 0.f) ? __builtin_amdgcn_rsqf(V0) : 1.0f;
      float z   = a * rs;
      float eu  = __builtin_amdgcn_exp2f(-0.5f * L2E * z * z);
      float el  = __builtin_amdgcn_exp2f(-LOGI_K * L2E * z);
      float Phi = __builtin_amdgcn_rcpf(1.0f + el);
      t0 = pi_w * fmaf(z, Phi, INV_SQRT_2PI * eu);
    }
    {
      float a   = bb[1] + bi[1] + A1;
      float rs  = (V1 > 0.f) ? __builtin_amdgcn_rsqf(V1) : 1.0f;
      float z   = a * rs;
      float eu  = __builtin_amdgcn_exp2f(-0.5f * L2E * z * z);
      float el  = __builtin_amdgcn_exp2f(-LOGI_K * L2E * z);
      float Phi = __builtin_amdgcn_rcpf(1.0f + el);
      t1 = pi_w * fmaf(z, Phi, INV_SQRT_2PI * eu);
    }
#pragma unroll
    for (int d = 1; d <= 4; d <<= 1) {
      t0 += __shfl_xor(t0, d);
      t1 += __shfl_xor(t1, d);
    }
    if (ii == 0) {
      f32x2 o; o[0] = t0; o[1] = t1;
      *(f32x2*)(io + (size_t)row * OUT + c) = o;
    }
  }
}

// ---------------------------------------------------------------------------
extern "C" void kernel_launch(void* const* d_in, const int* in_sizes, int n_in,
                              void* d_out, int out_size, void* d_ws, size_t ws_size,
                              hipStream_t stream) {
  const float* x  = (const float*)d_in[0];
  const float* W  = (const float*)d_in[1];
  const float* b  = (const float*)d_in[2];
  const float* gw = (const float*)d_in[3];
  const float* gm = (const float*)d_in[4];
  const float* gc = (const float*)d_in[5];
  float* out = (float*)d_out;
  const int M = in_sizes[0] / IN;  // 8192

  // workspace layout: ~5.6 MB total (no xb; W16 fits safely)
  char* ws = (char*)d_ws;
  size_t off = 0;
  unsigned short* Wt   = (unsigned short*)(ws + off); off += (size_t)IN * OUT * 2;   // 2 MB
  unsigned short* W16  = (unsigned short*)(ws + off); off += (size_t)IN * OUT * 2;   // 2 MB
  unsigned short* midx = (unsigned short*)(ws + off); off += (size_t)M * MAXM * 2;   // 1.5 MB
  int* counts          = (int*)(ws + off);            off += (size_t)M * 4;          // 32 KB
  float* p_ws          = (float*)(ws + off);          off += 256;

  prep_kernel<<<M, 256, 0, stream>>>(x, midx, counts);
  transpose_w<<<dim3(IN / 32, OUT / 32), dim3(32, 8), 0, stream>>>(W, Wt, W16, gw, p_ws);
  gemm_base<<<dim3(M / 128, OUT / 128), 256, 0, stream>>>(x, Wt, out, M);
  epilogue_mfma7<<<dim3(M, 2), 256, 0, stream>>>(out, W16, b, p_ws, gm, gc, midx, counts);
}